// Round 8
// baseline (363.144 us; speedup 1.0000x reference)
//
#include <hip/hip_runtime.h>

#define CAP 64
#define OVF_MAX 8192
#define CSTRIDE 16   // ints per node counter (64B line) — atomic line-spreading

// ---------------- helpers ----------------

// Stage W (64x64 row-major) into LDS as lane-contiguous float4 blocks:
// Wt2 float4[q*64 + l] = (W[4q][l], W[4q+1][l], W[4q+2][l], W[4q+3][l]).
// Read pattern wt4[q*64 + l] is lane-consecutive 16B -> conflict-free b128.
__device__ __forceinline__ void stage_Wt2(const float* __restrict__ W,
                                          float* __restrict__ Wt2dw, int tid) {
    const float4* W4 = (const float4*)W;
    #pragma unroll
    for (int i4 = 0; i4 < 4; ++i4) {
        int f4 = i4 * 256 + tid;
        float4 v = W4[f4];
        int i  = f4 >> 4;                  // row of W
        int c4 = f4 & 15;                  // col group
        int base = (i >> 2) * 256 + (i & 3);
        Wt2dw[base + (4 * c4 + 0) * 4] = v.x;
        Wt2dw[base + (4 * c4 + 1) * 4] = v.y;
        Wt2dw[base + (4 * c4 + 2) * 4] = v.z;
        Wt2dw[base + (4 * c4 + 3) * 4] = v.w;
    }
}

// ---------------- kernels ----------------

// Prelude: zero padded cur + ovfc; 16 blocks compute Wc = W2@Wout; 1 block bc.
__global__ void k_pre(int* __restrict__ cur, int* __restrict__ ovfc, int N,
                      const float* __restrict__ W2, const float* __restrict__ Wout,
                      const float* __restrict__ b2, const float* __restrict__ bout,
                      float* __restrict__ Wc, float* __restrict__ bc, int zb) {
    int tid = threadIdx.x;
    int bid = blockIdx.x;
    if (bid < zb) {
        int i = bid * 256 + tid;
        if (i < N * CSTRIDE) cur[i] = 0;
        if (i == N * CSTRIDE) *ovfc = 0;
        return;
    }
    int wb = bid - zb;
    if (wb < 16) {
        int idx = wb * 256 + tid;
        int j = idx >> 6, i = idx & 63;
        float s = 0.0f;
        #pragma unroll 8
        for (int m = 0; m < 64; ++m)
            s = fmaf(W2[i * 64 + m], Wout[m * 64 + j], s);
        Wc[i * 64 + j] = s;
    } else if (tid < 64) {
        float s = bout[tid];
        for (int k = 0; k < 64; ++k)
            s = fmaf(b2[k], Wout[k * 64 + tid], s);
        bc[tid] = s;
    }
}

// Fat kernel:
//  blocks [0, scatterBlocks): bucket edges by dst (one atomic per edge)
//  blocks [scatterBlocks, ..): h1 = mean_t(x) @ W1 (coalesced x, LDS GEMM)
__global__ __launch_bounds__(256) void k_scatmean(
        const int* __restrict__ ei, const float* __restrict__ ea,
        int* __restrict__ cur, int2* __restrict__ eb,
        int* __restrict__ ovf_cnt, int4* __restrict__ ovf,
        int E, int scatterBlocks,
        const float* __restrict__ x, const float* __restrict__ W1,
        float* __restrict__ h1, int N) {
    int tid = threadIdx.x;
    if ((int)blockIdx.x < scatterBlocks) {
        int e = blockIdx.x * 256 + tid;
        if (e < E) {
            int s = ei[e];
            int d = ei[E + e];
            float w = ea[(size_t)e * 16 + 15];
            int p = atomicAdd(cur + (size_t)d * CSTRIDE, 1);
            if (p < CAP) {
                eb[(size_t)d * CAP + p] = make_int2(s, __float_as_int(w));
            } else {
                int q = atomicAdd(ovf_cnt, 1);
                if (q < OVF_MAX) ovf[q] = make_int4(s, d, __float_as_int(w), 0);
            }
        }
        return;
    }
    __shared__ float Wt2[4096];              // W1 in lane-contiguous blocks
    __shared__ float rbuf[4 * 4 * 64];       // [wave][it][64] xa staging
    stage_Wt2(W1, Wt2, tid);
    __syncthreads();
    int bid = (int)blockIdx.x - scatterBlocks;
    int w = tid >> 6, l = tid & 63;
    float* rw = rbuf + w * 256;
    int n0 = bid * 16 + w;                   // wave-uniform; +4 per it
    // phase 1: compute xa for 4 nodes, stage in rbuf
    #pragma unroll
    for (int it = 0; it < 4; ++it) {
        int n = n0 + it * 4;
        if (n >= N) continue;
        // coalesced 1KB reads; float4 #(k*64+l) lies in channel c = k*16 + (l>>2)
        const float4* xp = (const float4*)(x + (size_t)n * 1024);
        float4 v0 = xp[l], v1 = xp[64 + l], v2 = xp[128 + l], v3 = xp[192 + l];
        float s0 = (v0.x + v0.y) + (v0.z + v0.w);
        float s1 = (v1.x + v1.y) + (v1.z + v1.w);
        float s2 = (v2.x + v2.y) + (v2.z + v2.w);
        float s3 = (v3.x + v3.y) + (v3.z + v3.w);
        s0 += __shfl_xor(s0, 1); s0 += __shfl_xor(s0, 2);
        s1 += __shfl_xor(s1, 1); s1 += __shfl_xor(s1, 2);
        s2 += __shfl_xor(s2, 1); s2 += __shfl_xor(s2, 2);
        s3 += __shfl_xor(s3, 1); s3 += __shfl_xor(s3, 2);
        if ((l & 3) == 0) {                  // quad leader: channels q,16+q,32+q,48+q
            int q = l >> 2;
            float* r = rw + it * 64;
            r[q]      = s0 * 0.0625f;
            r[q + 16] = s1 * 0.0625f;
            r[q + 32] = s2 * 0.0625f;
            r[q + 48] = s3 * 0.0625f;
        }
    }
    // phase 2: batched GEMM — W read once, applied to 4 nodes
    float acc0 = 0.f, acc1 = 0.f, acc2 = 0.f, acc3 = 0.f;
    const float4* wt4 = (const float4*)Wt2;
    const float4* rb0 = (const float4*)(rw);
    const float4* rb1 = (const float4*)(rw + 64);
    const float4* rb2 = (const float4*)(rw + 128);
    const float4* rb3 = (const float4*)(rw + 192);
    #pragma unroll
    for (int q = 0; q < 16; ++q) {
        float4 wv = wt4[q * 64 + l];         // lane-contiguous: conflict-free
        float4 r0 = rb0[q], r1 = rb1[q], r2 = rb2[q], r3 = rb3[q];  // broadcasts
        acc0 = fmaf(r0.x, wv.x, acc0); acc0 = fmaf(r0.y, wv.y, acc0);
        acc0 = fmaf(r0.z, wv.z, acc0); acc0 = fmaf(r0.w, wv.w, acc0);
        acc1 = fmaf(r1.x, wv.x, acc1); acc1 = fmaf(r1.y, wv.y, acc1);
        acc1 = fmaf(r1.z, wv.z, acc1); acc1 = fmaf(r1.w, wv.w, acc1);
        acc2 = fmaf(r2.x, wv.x, acc2); acc2 = fmaf(r2.y, wv.y, acc2);
        acc2 = fmaf(r2.z, wv.z, acc2); acc2 = fmaf(r2.w, wv.w, acc2);
        acc3 = fmaf(r3.x, wv.x, acc3); acc3 = fmaf(r3.y, wv.y, acc3);
        acc3 = fmaf(r3.z, wv.z, acc3); acc3 = fmaf(r3.w, wv.w, acc3);
    }
    if (n0 < N)      h1[(size_t)(n0     ) * 64 + l] = acc0;
    if (n0 + 4 < N)  h1[(size_t)(n0 + 4 ) * 64 + l] = acc1;
    if (n0 + 8 < N)  h1[(size_t)(n0 + 8 ) * 64 + l] = acc2;
    if (n0 + 12 < N) h1[(size_t)(n0 + 12) * 64 + l] = acc3;
}

// dinv[n] = 1/sqrt(1 + sum of ew over node n's bucket). 4 lanes per node.
__global__ void k_dinvb(const int* __restrict__ cur, const int2* __restrict__ eb,
                        const int* __restrict__ ovf_cnt, const int4* __restrict__ ovf,
                        float* __restrict__ dinv, int N) {
    int tid = threadIdx.x;
    int n = blockIdx.x * 64 + (tid >> 2);
    int j = tid & 3;
    if (n >= N) return;
    int mfull = cur[(size_t)n * CSTRIDE];
    int m = mfull > CAP ? CAP : mfull;
    float s = 0.0f;
    for (int i = j; i < m; i += 4) s += __int_as_float(eb[(size_t)n * CAP + i].y);
    s += __shfl_xor(s, 1);
    s += __shfl_xor(s, 2);
    if (j == 0) {
        if (mfull > CAP) {
            int oc = *ovf_cnt; if (oc > OVF_MAX) oc = OVF_MAX;
            for (int k = 0; k < oc; ++k) {
                int4 o = ovf[k];
                if (o.y == n) s += __int_as_float(o.z);
            }
        }
        dinv[n] = 1.0f / sqrtf(s + 1.0f);
    }
}

// Layer-1: pure gather + bias + relu (GEMM folded out). One wave per node.
__global__ __launch_bounds__(256) void k_agg1(const float* __restrict__ in,
                                              const float* __restrict__ bias,
                                              const float* __restrict__ dinv,
                                              const int* __restrict__ cur,
                                              const int2* __restrict__ eb,
                                              const int* __restrict__ ovf_cnt,
                                              const int4* __restrict__ ovf,
                                              float* __restrict__ out, int N) {
    int tid = threadIdx.x;
    int w = tid >> 6, c = tid & 63;
    float bias_c = bias[c];
    for (int it = 0; it < 4; ++it) {
        int n = blockIdx.x * 16 + it * 4 + w;
        if (n >= N) continue;
        float dv = dinv[n];
        float selfv = in[(size_t)n * 64 + c];
        float a0 = 0.f, a1 = 0.f, a2 = 0.f, a3 = 0.f;
        const int2* bkt = eb + (size_t)n * CAP;
        int mfull = cur[(size_t)n * CSTRIDE];
        int m = mfull > CAP ? CAP : mfull;
        int i = 0;
        for (; i + 8 <= m; i += 8) {
            int2 e0 = bkt[i + 0], e1 = bkt[i + 1], e2 = bkt[i + 2], e3 = bkt[i + 3];
            int2 e4 = bkt[i + 4], e5 = bkt[i + 5], e6 = bkt[i + 6], e7 = bkt[i + 7];
            float d0 = dinv[e0.x], d1 = dinv[e1.x], d2 = dinv[e2.x], d3 = dinv[e3.x];
            float d4 = dinv[e4.x], d5 = dinv[e5.x], d6 = dinv[e6.x], d7 = dinv[e7.x];
            float v0 = in[(size_t)e0.x * 64 + c], v1 = in[(size_t)e1.x * 64 + c];
            float v2 = in[(size_t)e2.x * 64 + c], v3 = in[(size_t)e3.x * 64 + c];
            float v4 = in[(size_t)e4.x * 64 + c], v5 = in[(size_t)e5.x * 64 + c];
            float v6 = in[(size_t)e6.x * 64 + c], v7 = in[(size_t)e7.x * 64 + c];
            a0 = fmaf(v0, __int_as_float(e0.y) * d0, a0);
            a1 = fmaf(v1, __int_as_float(e1.y) * d1, a1);
            a2 = fmaf(v2, __int_as_float(e2.y) * d2, a2);
            a3 = fmaf(v3, __int_as_float(e3.y) * d3, a3);
            a0 = fmaf(v4, __int_as_float(e4.y) * d4, a0);
            a1 = fmaf(v5, __int_as_float(e5.y) * d5, a1);
            a2 = fmaf(v6, __int_as_float(e6.y) * d6, a2);
            a3 = fmaf(v7, __int_as_float(e7.y) * d7, a3);
        }
        for (; i < m; ++i) {
            int2 e = bkt[i];
            a0 = fmaf(in[(size_t)e.x * 64 + c], __int_as_float(e.y) * dinv[e.x], a0);
        }
        if (mfull > CAP) {                   // wave-uniform, ~never taken
            int oc = *ovf_cnt; if (oc > OVF_MAX) oc = OVF_MAX;
            for (int k = 0; k < oc; ++k) {
                int4 o = ovf[k];
                if (o.y == n)
                    a0 = fmaf(in[(size_t)o.x * 64 + c], __int_as_float(o.z) * dinv[o.x], a0);
            }
        }
        float r = fmaf(dv, ((a0 + a1) + (a2 + a3)) + selfv * dv, bias_c);
        out[(size_t)n * 64 + c] = fmaxf(r, 0.0f);
    }
}

// Layer-2: gather + batched LDS GEMM (Wc) + bc -> final output.
__global__ __launch_bounds__(256) void k_agg2(const float* __restrict__ in,
                                              const float* __restrict__ Wc,
                                              const float* __restrict__ bc,
                                              const float* __restrict__ dinv,
                                              const int* __restrict__ cur,
                                              const int2* __restrict__ eb,
                                              const int* __restrict__ ovf_cnt,
                                              const int4* __restrict__ ovf,
                                              float* __restrict__ out, int N) {
    __shared__ float Wt2[4096];
    __shared__ float rbuf[4 * 4 * 64];
    int tid = threadIdx.x;
    stage_Wt2(Wc, Wt2, tid);
    __syncthreads();
    int w = tid >> 6, c = tid & 63;
    float bc_c = bc[c];
    float* rw = rbuf + w * 256;
    int n0 = blockIdx.x * 16 + w;
    // phase 1: gather r for 4 nodes, stage in rbuf
    #pragma unroll
    for (int it = 0; it < 4; ++it) {
        int n = n0 + it * 4;
        if (n >= N) continue;
        float dv = dinv[n];
        float selfv = in[(size_t)n * 64 + c];
        float a0 = 0.f, a1 = 0.f, a2 = 0.f, a3 = 0.f;
        const int2* bkt = eb + (size_t)n * CAP;
        int mfull = cur[(size_t)n * CSTRIDE];
        int m = mfull > CAP ? CAP : mfull;
        int i = 0;
        for (; i + 8 <= m; i += 8) {
            int2 e0 = bkt[i + 0], e1 = bkt[i + 1], e2 = bkt[i + 2], e3 = bkt[i + 3];
            int2 e4 = bkt[i + 4], e5 = bkt[i + 5], e6 = bkt[i + 6], e7 = bkt[i + 7];
            float d0 = dinv[e0.x], d1 = dinv[e1.x], d2 = dinv[e2.x], d3 = dinv[e3.x];
            float d4 = dinv[e4.x], d5 = dinv[e5.x], d6 = dinv[e6.x], d7 = dinv[e7.x];
            float v0 = in[(size_t)e0.x * 64 + c], v1 = in[(size_t)e1.x * 64 + c];
            float v2 = in[(size_t)e2.x * 64 + c], v3 = in[(size_t)e3.x * 64 + c];
            float v4 = in[(size_t)e4.x * 64 + c], v5 = in[(size_t)e5.x * 64 + c];
            float v6 = in[(size_t)e6.x * 64 + c], v7 = in[(size_t)e7.x * 64 + c];
            a0 = fmaf(v0, __int_as_float(e0.y) * d0, a0);
            a1 = fmaf(v1, __int_as_float(e1.y) * d1, a1);
            a2 = fmaf(v2, __int_as_float(e2.y) * d2, a2);
            a3 = fmaf(v3, __int_as_float(e3.y) * d3, a3);
            a0 = fmaf(v4, __int_as_float(e4.y) * d4, a0);
            a1 = fmaf(v5, __int_as_float(e5.y) * d5, a1);
            a2 = fmaf(v6, __int_as_float(e6.y) * d6, a2);
            a3 = fmaf(v7, __int_as_float(e7.y) * d7, a3);
        }
        for (; i < m; ++i) {
            int2 e = bkt[i];
            a0 = fmaf(in[(size_t)e.x * 64 + c], __int_as_float(e.y) * dinv[e.x], a0);
        }
        if (mfull > CAP) {
            int oc = *ovf_cnt; if (oc > OVF_MAX) oc = OVF_MAX;
            for (int k = 0; k < oc; ++k) {
                int4 o = ovf[k];
                if (o.y == n)
                    a0 = fmaf(in[(size_t)o.x * 64 + c], __int_as_float(o.z) * dinv[o.x], a0);
            }
        }
        rw[it * 64 + c] = dv * (((a0 + a1) + (a2 + a3)) + selfv * dv);
    }
    // phase 2: batched GEMM — W read once, applied to 4 nodes
    float acc0 = bc_c, acc1 = bc_c, acc2 = bc_c, acc3 = bc_c;
    const float4* wt4 = (const float4*)Wt2;
    const float4* rb0 = (const float4*)(rw);
    const float4* rb1 = (const float4*)(rw + 64);
    const float4* rb2 = (const float4*)(rw + 128);
    const float4* rb3 = (const float4*)(rw + 192);
    #pragma unroll
    for (int q = 0; q < 16; ++q) {
        float4 wv = wt4[q * 64 + c];
        float4 r0 = rb0[q], r1 = rb1[q], r2 = rb2[q], r3 = rb3[q];
        acc0 = fmaf(r0.x, wv.x, acc0); acc0 = fmaf(r0.y, wv.y, acc0);
        acc0 = fmaf(r0.z, wv.z, acc0); acc0 = fmaf(r0.w, wv.w, acc0);
        acc1 = fmaf(r1.x, wv.x, acc1); acc1 = fmaf(r1.y, wv.y, acc1);
        acc1 = fmaf(r1.z, wv.z, acc1); acc1 = fmaf(r1.w, wv.w, acc1);
        acc2 = fmaf(r2.x, wv.x, acc2); acc2 = fmaf(r2.y, wv.y, acc2);
        acc2 = fmaf(r2.z, wv.z, acc2); acc2 = fmaf(r2.w, wv.w, acc2);
        acc3 = fmaf(r3.x, wv.x, acc3); acc3 = fmaf(r3.y, wv.y, acc3);
        acc3 = fmaf(r3.z, wv.z, acc3); acc3 = fmaf(r3.w, wv.w, acc3);
    }
    if (n0 < N)      out[(size_t)(n0     ) * 64 + c] = acc0;
    if (n0 + 4 < N)  out[(size_t)(n0 + 4 ) * 64 + c] = acc1;
    if (n0 + 8 < N)  out[(size_t)(n0 + 8 ) * 64 + c] = acc2;
    if (n0 + 12 < N) out[(size_t)(n0 + 12) * 64 + c] = acc3;
}

// ---------------- launcher ----------------

extern "C" void kernel_launch(void* const* d_in, const int* in_sizes, int n_in,
                              void* d_out, int out_size, void* d_ws, size_t ws_size,
                              hipStream_t stream) {
    const float* x    = (const float*)d_in[0];
    const int*   ei   = (const int*)d_in[1];
    const float* ea   = (const float*)d_in[2];
    const float* W1   = (const float*)d_in[3];
    const float* b1   = (const float*)d_in[4];
    const float* W2   = (const float*)d_in[5];
    const float* b2   = (const float*)d_in[6];
    const float* Wout = (const float*)d_in[7];
    const float* bout = (const float*)d_in[8];
    float* out = (float*)d_out;

    const int N = in_sizes[0] / (64 * 16);   // 50000
    const int E = in_sizes[1] / 2;           // 800000

    // workspace layout
    char* wsb = (char*)d_ws;
    int4*  ovf  = (int4*)wsb;                       // 128KB
    int2*  eb   = (int2*)(wsb + OVF_MAX * 16);      // N*CAP*8B
    float* H1   = (float*)(wsb + OVF_MAX * 16 + (size_t)N * CAP * 8);
    size_t NC = (size_t)N * 64;
    float* Z    = H1 + NC;
    int*   cur  = (int*)(Z + NC);                   // N*CSTRIDE ints (3.2MB)
    float* dinv = (float*)(cur + (size_t)N * CSTRIDE);
    int*   ovfc = (int*)(dinv + N);
    float* Wc   = (float*)(ovfc + 4);
    float* bc   = Wc + 4096;

    dim3 b256(256);
    int meanBlocks    = (N + 15) / 16;       // 3125
    int scatterBlocks = (E + 255) / 256;     // 3125
    int zb = (N * CSTRIDE + 256) / 256;      // covers i == N*CSTRIDE

    hipLaunchKernelGGL(k_pre, dim3(zb + 17), b256, 0, stream,
                       cur, ovfc, N, W2, Wout, b2, bout, Wc, bc, zb);
    hipLaunchKernelGGL(k_scatmean, dim3(scatterBlocks + meanBlocks), b256, 0, stream,
                       ei, ea, cur, eb, ovfc, ovf, E, scatterBlocks, x, W1, H1, N);
    hipLaunchKernelGGL(k_dinvb, dim3((N + 63) / 64), b256, 0, stream,
                       cur, eb, ovfc, ovf, dinv, N);
    // layer 1: z = relu(agg(h1) + b1)          (W1 already applied in mean)
    hipLaunchKernelGGL(k_agg1, dim3(meanBlocks), b256, 0, stream,
                       H1, b1, dinv, cur, eb, ovfc, ovf, Z, N);
    // layer 2+out: out = agg(z) @ Wc + bc
    hipLaunchKernelGGL(k_agg2, dim3(meanBlocks), b256, 0, stream,
                       Z, Wc, bc, dinv, cur, eb, ovfc, ovf, out, N);
}

// Round 9
// 185.893 us; speedup vs baseline: 1.9535x; 1.9535x over previous
//
#include <hip/hip_runtime.h>

#define CAP 64
#define OVF_MAX 8192

// ---------------- helpers ----------------

// Conflict-free stage of W (64x64 row-major) into LDS:
//   Wt[q*64 + l] = float4(W[4q][l], W[4q+1][l], W[4q+2][l], W[4q+3][l])
// Global loads: per (q,j) one coalesced 256B row read. LDS writes: contiguous
// per-lane float4 -> canonical conflict-free pattern. Reads in the GEMM
// (Wt[q*64+l]) are likewise contiguous -> conflict-free.
__device__ __forceinline__ void stage_W(const float* __restrict__ W,
                                        float4* __restrict__ Wt, int tid) {
    int l = tid & 63, qq = tid >> 6;
    #pragma unroll
    for (int s = 0; s < 4; ++s) {
        int q = qq * 4 + s;                 // 0..15
        float4 v = make_float4(W[(4 * q + 0) * 64 + l],
                               W[(4 * q + 1) * 64 + l],
                               W[(4 * q + 2) * 64 + l],
                               W[(4 * q + 3) * 64 + l]);
        Wt[q * 64 + l] = v;
    }
}

// ---------------- kernels ----------------

// Prelude: zero cur/ovfc; 16 blocks compute Wc = W2@Wout; 1 block bc.
__global__ void k_pre(int* __restrict__ cur, int* __restrict__ ovfc, int N,
                      const float* __restrict__ W2, const float* __restrict__ Wout,
                      const float* __restrict__ b2, const float* __restrict__ bout,
                      float* __restrict__ Wc, float* __restrict__ bc, int zb) {
    int tid = threadIdx.x;
    int bid = blockIdx.x;
    if (bid < zb) {
        int i = bid * 256 + tid;
        if (i < N) cur[i] = 0;
        if (i == N) *ovfc = 0;
        return;
    }
    int wb = bid - zb;
    if (wb < 16) {
        int idx = wb * 256 + tid;
        int j = idx >> 6, i = idx & 63;
        float s = 0.0f;
        #pragma unroll 8
        for (int m = 0; m < 64; ++m)
            s = fmaf(W2[i * 64 + m], Wout[m * 64 + j], s);
        Wc[i * 64 + j] = s;
    } else if (tid < 64) {
        float s = bout[tid];
        for (int k = 0; k < 64; ++k)
            s = fmaf(b2[k], Wout[k * 64 + tid], s);
        bc[tid] = s;
    }
}

// Fat kernel, roles interleaved by parity so the latency-bound scatter and the
// BW/DS-bound mean+GEMM co-run on every CU:
//  even blocks: bucket edges by dst (one atomic per edge)
//  odd  blocks: h1 = mean_t(x) @ W1  (coalesced x reads, conflict-free LDS GEMM)
__global__ __launch_bounds__(256) void k_scatmean(
        const int* __restrict__ ei, const float* __restrict__ ea,
        int* __restrict__ cur, int2* __restrict__ eb,
        int* __restrict__ ovf_cnt, int4* __restrict__ ovf,
        int E, int scatterBlocks,
        const float* __restrict__ x, const float* __restrict__ W1,
        float* __restrict__ h1, int N, int meanBlocks) {
    int tid = threadIdx.x;
    int bid = (int)blockIdx.x;
    int nmin = scatterBlocks < meanBlocks ? scatterBlocks : meanBlocks;
    int isScat, rid;
    if (bid < 2 * nmin) { isScat = !(bid & 1); rid = bid >> 1; }
    else { isScat = (scatterBlocks > meanBlocks); rid = bid - 2 * nmin + nmin; }

    if (isScat) {
        int e = rid * 256 + tid;
        if (e < E) {
            int s = ei[e];
            int d = ei[E + e];
            float w = ea[(size_t)e * 16 + 15];
            int p = atomicAdd(cur + d, 1);
            if (p < CAP) {
                eb[(size_t)d * CAP + p] = make_int2(s, __float_as_int(w));
            } else {
                int q = atomicAdd(ovf_cnt, 1);
                if (q < OVF_MAX) ovf[q] = make_int4(s, d, __float_as_int(w), 0);
            }
        }
        return;
    }
    __shared__ float4 Wt[16 * 64];           // 16KB, conflict-free layout
    __shared__ float rbuf[4 * 64];
    stage_W(W1, Wt, tid);
    __syncthreads();
    int w = tid >> 6, l = tid & 63;
    float* rw = rbuf + w * 64;
    for (int it = 0; it < 4; ++it) {         // NOT unrolled: keep VGPRs lean
        int n = rid * 16 + it * 4 + w;       // wave-uniform
        if (n >= N) continue;
        // coalesced 1KB reads; float4 #(k*64+l) lies in channel c = k*16 + (l>>2)
        const float4* xp = (const float4*)(x + (size_t)n * 1024);
        float4 v0 = xp[l], v1 = xp[64 + l], v2 = xp[128 + l], v3 = xp[192 + l];
        float s0 = (v0.x + v0.y) + (v0.z + v0.w);
        float s1 = (v1.x + v1.y) + (v1.z + v1.w);
        float s2 = (v2.x + v2.y) + (v2.z + v2.w);
        float s3 = (v3.x + v3.y) + (v3.z + v3.w);
        s0 += __shfl_xor(s0, 1); s0 += __shfl_xor(s0, 2);
        s1 += __shfl_xor(s1, 1); s1 += __shfl_xor(s1, 2);
        s2 += __shfl_xor(s2, 1); s2 += __shfl_xor(s2, 2);
        s3 += __shfl_xor(s3, 1); s3 += __shfl_xor(s3, 2);
        if ((l & 3) == 0) {                  // quad leader: channels q,16+q,32+q,48+q
            int q = l >> 2;
            rw[q]      = s0 * 0.0625f;
            rw[q + 16] = s1 * 0.0625f;
            rw[q + 32] = s2 * 0.0625f;
            rw[q + 48] = s3 * 0.0625f;
        }
        float acc = 0.0f;
        const float4* rb4 = (const float4*)rw;
        #pragma unroll
        for (int q = 0; q < 16; ++q) {
            float4 rv = rb4[q];              // broadcast (same addr all lanes)
            float4 wv = Wt[q * 64 + l];      // contiguous: conflict-free
            acc = fmaf(rv.x, wv.x, acc);
            acc = fmaf(rv.y, wv.y, acc);
            acc = fmaf(rv.z, wv.z, acc);
            acc = fmaf(rv.w, wv.w, acc);
        }
        h1[(size_t)n * 64 + l] = acc;
    }
}

// dinv[n] = 1/sqrt(1 + sum of ew over node n's bucket). 4 lanes per node.
__global__ void k_dinvb(const int* __restrict__ cur, const int2* __restrict__ eb,
                        const int* __restrict__ ovf_cnt, const int4* __restrict__ ovf,
                        float* __restrict__ dinv, int N) {
    int tid = threadIdx.x;
    int n = blockIdx.x * 64 + (tid >> 2);
    int j = tid & 3;
    if (n >= N) return;
    int mfull = cur[n];
    int m = mfull > CAP ? CAP : mfull;
    float s = 0.0f;
    for (int i = j; i < m; i += 4) s += __int_as_float(eb[(size_t)n * CAP + i].y);
    s += __shfl_xor(s, 1);
    s += __shfl_xor(s, 2);
    if (j == 0) {
        if (mfull > CAP) {
            int oc = *ovf_cnt; if (oc > OVF_MAX) oc = OVF_MAX;
            for (int k = 0; k < oc; ++k) {
                int4 o = ovf[k];
                if (o.y == n) s += __int_as_float(o.z);
            }
        }
        dinv[n] = 1.0f / sqrtf(s + 1.0f);
    }
}

// Layer-1: pure gather + bias + relu (W1 already applied upstream). One wave/node.
__global__ __launch_bounds__(256) void k_agg1(const float* __restrict__ in,
                                              const float* __restrict__ bias,
                                              const float* __restrict__ dinv,
                                              const int* __restrict__ cur,
                                              const int2* __restrict__ eb,
                                              const int* __restrict__ ovf_cnt,
                                              const int4* __restrict__ ovf,
                                              float* __restrict__ out, int N) {
    int tid = threadIdx.x;
    int w = tid >> 6, c = tid & 63;
    float bias_c = bias[c];
    for (int it = 0; it < 4; ++it) {
        int n = blockIdx.x * 16 + it * 4 + w;
        if (n >= N) continue;
        float dv = dinv[n];
        float selfv = in[(size_t)n * 64 + c];
        float a0 = 0.f, a1 = 0.f, a2 = 0.f, a3 = 0.f;
        const int2* bkt = eb + (size_t)n * CAP;
        int mfull = cur[n];
        int m = mfull > CAP ? CAP : mfull;
        int i = 0;
        for (; i + 8 <= m; i += 8) {
            int2 e0 = bkt[i + 0], e1 = bkt[i + 1], e2 = bkt[i + 2], e3 = bkt[i + 3];
            int2 e4 = bkt[i + 4], e5 = bkt[i + 5], e6 = bkt[i + 6], e7 = bkt[i + 7];
            float d0 = dinv[e0.x], d1 = dinv[e1.x], d2 = dinv[e2.x], d3 = dinv[e3.x];
            float d4 = dinv[e4.x], d5 = dinv[e5.x], d6 = dinv[e6.x], d7 = dinv[e7.x];
            float v0 = in[(size_t)e0.x * 64 + c], v1 = in[(size_t)e1.x * 64 + c];
            float v2 = in[(size_t)e2.x * 64 + c], v3 = in[(size_t)e3.x * 64 + c];
            float v4 = in[(size_t)e4.x * 64 + c], v5 = in[(size_t)e5.x * 64 + c];
            float v6 = in[(size_t)e6.x * 64 + c], v7 = in[(size_t)e7.x * 64 + c];
            a0 = fmaf(v0, __int_as_float(e0.y) * d0, a0);
            a1 = fmaf(v1, __int_as_float(e1.y) * d1, a1);
            a2 = fmaf(v2, __int_as_float(e2.y) * d2, a2);
            a3 = fmaf(v3, __int_as_float(e3.y) * d3, a3);
            a0 = fmaf(v4, __int_as_float(e4.y) * d4, a0);
            a1 = fmaf(v5, __int_as_float(e5.y) * d5, a1);
            a2 = fmaf(v6, __int_as_float(e6.y) * d6, a2);
            a3 = fmaf(v7, __int_as_float(e7.y) * d7, a3);
        }
        for (; i < m; ++i) {
            int2 e = bkt[i];
            a0 = fmaf(in[(size_t)e.x * 64 + c], __int_as_float(e.y) * dinv[e.x], a0);
        }
        if (mfull > CAP) {                   // wave-uniform, ~never taken
            int oc = *ovf_cnt; if (oc > OVF_MAX) oc = OVF_MAX;
            for (int k = 0; k < oc; ++k) {
                int4 o = ovf[k];
                if (o.y == n)
                    a0 = fmaf(in[(size_t)o.x * 64 + c], __int_as_float(o.z) * dinv[o.x], a0);
            }
        }
        float r = fmaf(dv, ((a0 + a1) + (a2 + a3)) + selfv * dv, bias_c);
        out[(size_t)n * 64 + c] = fmaxf(r, 0.0f);
    }
}

// Layer-2: gather + per-node conflict-free LDS GEMM (Wc) + bc -> final output.
__global__ __launch_bounds__(256) void k_agg2(const float* __restrict__ in,
                                              const float* __restrict__ Wc,
                                              const float* __restrict__ bc,
                                              const float* __restrict__ dinv,
                                              const int* __restrict__ cur,
                                              const int2* __restrict__ eb,
                                              const int* __restrict__ ovf_cnt,
                                              const int4* __restrict__ ovf,
                                              float* __restrict__ out, int N) {
    __shared__ float4 Wt[16 * 64];
    __shared__ float rbuf[4 * 64];
    int tid = threadIdx.x;
    stage_W(Wc, Wt, tid);
    __syncthreads();
    int w = tid >> 6, c = tid & 63;
    float bc_c = bc[c];
    float* rw = rbuf + w * 64;
    for (int it = 0; it < 4; ++it) {         // NOT unrolled
        int n = blockIdx.x * 16 + it * 4 + w;
        if (n >= N) continue;
        float dv = dinv[n];
        float selfv = in[(size_t)n * 64 + c];
        float a0 = 0.f, a1 = 0.f, a2 = 0.f, a3 = 0.f;
        const int2* bkt = eb + (size_t)n * CAP;
        int mfull = cur[n];
        int m = mfull > CAP ? CAP : mfull;
        int i = 0;
        for (; i + 8 <= m; i += 8) {
            int2 e0 = bkt[i + 0], e1 = bkt[i + 1], e2 = bkt[i + 2], e3 = bkt[i + 3];
            int2 e4 = bkt[i + 4], e5 = bkt[i + 5], e6 = bkt[i + 6], e7 = bkt[i + 7];
            float d0 = dinv[e0.x], d1 = dinv[e1.x], d2 = dinv[e2.x], d3 = dinv[e3.x];
            float d4 = dinv[e4.x], d5 = dinv[e5.x], d6 = dinv[e6.x], d7 = dinv[e7.x];
            float v0 = in[(size_t)e0.x * 64 + c], v1 = in[(size_t)e1.x * 64 + c];
            float v2 = in[(size_t)e2.x * 64 + c], v3 = in[(size_t)e3.x * 64 + c];
            float v4 = in[(size_t)e4.x * 64 + c], v5 = in[(size_t)e5.x * 64 + c];
            float v6 = in[(size_t)e6.x * 64 + c], v7 = in[(size_t)e7.x * 64 + c];
            a0 = fmaf(v0, __int_as_float(e0.y) * d0, a0);
            a1 = fmaf(v1, __int_as_float(e1.y) * d1, a1);
            a2 = fmaf(v2, __int_as_float(e2.y) * d2, a2);
            a3 = fmaf(v3, __int_as_float(e3.y) * d3, a3);
            a0 = fmaf(v4, __int_as_float(e4.y) * d4, a0);
            a1 = fmaf(v5, __int_as_float(e5.y) * d5, a1);
            a2 = fmaf(v6, __int_as_float(e6.y) * d6, a2);
            a3 = fmaf(v7, __int_as_float(e7.y) * d7, a3);
        }
        for (; i < m; ++i) {
            int2 e = bkt[i];
            a0 = fmaf(in[(size_t)e.x * 64 + c], __int_as_float(e.y) * dinv[e.x], a0);
        }
        if (mfull > CAP) {
            int oc = *ovf_cnt; if (oc > OVF_MAX) oc = OVF_MAX;
            for (int k = 0; k < oc; ++k) {
                int4 o = ovf[k];
                if (o.y == n)
                    a0 = fmaf(in[(size_t)o.x * 64 + c], __int_as_float(o.z) * dinv[o.x], a0);
            }
        }
        float r = dv * (((a0 + a1) + (a2 + a3)) + selfv * dv);
        rw[c] = r;
        float acc = bc_c;
        const float4* rb4 = (const float4*)rw;
        #pragma unroll
        for (int q = 0; q < 16; ++q) {
            float4 rv = rb4[q];              // broadcast
            float4 wv = Wt[q * 64 + c];      // contiguous: conflict-free
            acc = fmaf(rv.x, wv.x, acc);
            acc = fmaf(rv.y, wv.y, acc);
            acc = fmaf(rv.z, wv.z, acc);
            acc = fmaf(rv.w, wv.w, acc);
        }
        out[(size_t)n * 64 + c] = acc;
    }
}

// ---------------- launcher ----------------

extern "C" void kernel_launch(void* const* d_in, const int* in_sizes, int n_in,
                              void* d_out, int out_size, void* d_ws, size_t ws_size,
                              hipStream_t stream) {
    const float* x    = (const float*)d_in[0];
    const int*   ei   = (const int*)d_in[1];
    const float* ea   = (const float*)d_in[2];
    const float* W1   = (const float*)d_in[3];
    const float* b1   = (const float*)d_in[4];
    const float* W2   = (const float*)d_in[5];
    const float* b2   = (const float*)d_in[6];
    const float* Wout = (const float*)d_in[7];
    const float* bout = (const float*)d_in[8];
    float* out = (float*)d_out;

    const int N = in_sizes[0] / (64 * 16);   // 50000
    const int E = in_sizes[1] / 2;           // 800000

    // workspace layout
    char* wsb = (char*)d_ws;
    int4*  ovf  = (int4*)wsb;                       // 128KB
    int2*  eb   = (int2*)(wsb + OVF_MAX * 16);      // N*CAP*8B
    float* H1   = (float*)(wsb + OVF_MAX * 16 + (size_t)N * CAP * 8);
    size_t NC = (size_t)N * 64;
    float* Z    = H1 + NC;
    int*   cur  = (int*)(Z + NC);
    float* dinv = (float*)(cur + N);
    int*   ovfc = (int*)(dinv + N);
    float* Wc   = (float*)(ovfc + 4);
    float* bc   = Wc + 4096;

    dim3 b256(256);
    int meanBlocks    = (N + 15) / 16;       // 3125
    int scatterBlocks = (E + 255) / 256;     // 3125
    int zb = (N + 256) / 256;                // covers i == N too

    hipLaunchKernelGGL(k_pre, dim3(zb + 17), b256, 0, stream,
                       cur, ovfc, N, W2, Wout, b2, bout, Wc, bc, zb);
    hipLaunchKernelGGL(k_scatmean, dim3(scatterBlocks + meanBlocks), b256, 0, stream,
                       ei, ea, cur, eb, ovfc, ovf, E, scatterBlocks, x, W1, H1, N, meanBlocks);
    hipLaunchKernelGGL(k_dinvb, dim3((N + 63) / 64), b256, 0, stream,
                       cur, eb, ovfc, ovf, dinv, N);
    // layer 1: z = relu(agg(h1) + b1)       (W1 applied in mean half)
    hipLaunchKernelGGL(k_agg1, dim3(meanBlocks), b256, 0, stream,
                       H1, b1, dinv, cur, eb, ovfc, ovf, Z, N);
    // layer 2+out: out = agg(z) @ Wc + bc
    hipLaunchKernelGGL(k_agg2, dim3(meanBlocks), b256, 0, stream,
                       Z, Wc, bc, dinv, cur, eb, ovfc, ovf, out, N);
}